// Round 15
// baseline (3526.187 us; speedup 1.0000x reference)
//
#include <hip/hip_runtime.h>

#define T_LEN 1024
#define HID   128
#define G4    512
#define NG    128      // fallback WGs
#define BCH   4        // fallback batch/WG
#define HB_STR 136     // halves per h buffer row (padded)

typedef _Float16 h2_t   __attribute__((ext_vector_type(2)));
typedef _Float16 f16x8  __attribute__((ext_vector_type(8)));
typedef float    f32x4n __attribute__((ext_vector_type(4)));

__device__ __forceinline__ float fsig(float v) {
  return __builtin_amdgcn_rcpf(1.0f + __expf(-v));
}
__device__ __forceinline__ float ftanh(float v) {
  float a = fabsf(v);
  float e = __expf(-2.0f * a);
  float t = (1.0f - e) * __builtin_amdgcn_rcpf(1.0f + e);
  return copysignf(t, v);
}
__device__ __forceinline__ float fdot2u(unsigned int a, unsigned int b, float c) {
  union { unsigned int u; h2_t h; } ca, cb;
  ca.u = a; cb.u = b;
  return __builtin_amdgcn_fdot2(ca.h, cb.h, c, false);
}

#define MFMA16(A, B, C) __builtin_amdgcn_mfma_f32_16x16x32_f16( \
    __builtin_bit_cast(f16x8, (A)), (B), (C), 0, 0, 0)

// ---------------------------------------------------------------------------
// Pack fp32 weights into MFMA A-fragments (fp16), gate-tiled per wave
// (identical to R5..R14 — validated): dst[((m*8+w)*16 + g*4+kt)*64 + l] =
// 8 halves of row = g*128 + 16w + (l&15), k = 32*kt + (l>>4)*8.
// m: 0=Whh1, 1=Whh2, 2=Wih2.
// ---------------------------------------------------------------------------
__global__ void __launch_bounds__(256) pack_frag2(
    const float* __restrict__ wa, const float* __restrict__ wb,
    const float* __restrict__ wc, uint4* __restrict__ dst) {
  int idx = blockIdx.x * 256 + threadIdx.x;   // 0..24575
  int l = idx & 63;
  int f = (idx >> 6) & 15;
  int w = (idx >> 10) & 7;
  int m = idx >> 13;
  const float* src = (m == 0) ? wa : (m == 1) ? wb : wc;
  int row = (f >> 2) * HID + 16 * w + (l & 15);
  int k0  = 32 * (f & 3) + (l >> 4) * 8;
  const float* s = src + (size_t)row * HID + k0;
  unsigned int r[4];
#pragma unroll
  for (int qq = 0; qq < 4; ++qq) {
    h2_t h;
    h.x = (_Float16)s[2 * qq];
    h.y = (_Float16)s[2 * qq + 1];
    r[qq] = __builtin_bit_cast(unsigned int, h);
  }
  dst[idx] = make_uint4(r[0], r[1], r[2], r[3]);
}

// ---------------------------------------------------------------------------
// R15 = R14 (in-lane act, 1 barrier) + wave0-fdot2 out (wo in regs, no
// DS shuffles on the other 7 waves) + split C2 chains (4-deep) + t-loop
// unrolled x2 (compile-time parity). 256 WGs x 512 thr, 2 batches/WG.
// ---------------------------------------------------------------------------
__global__ void __launch_bounds__(512, 2) lstm_v15(
    const float* __restrict__ xin, const float* __restrict__ Wih1,
    const float* __restrict__ bih1, const float* __restrict__ bhh1,
    const uint4* __restrict__ wfrag,
    const float* __restrict__ bih2, const float* __restrict__ bhh2,
    const float* __restrict__ Wout, const float* __restrict__ bout,
    float* __restrict__ outp)
{
  __shared__ __align__(16) _Float16 hB1[2][2 * HB_STR];  // [parity][batch][unit]
  __shared__ __align__(16) _Float16 hB2[2][2 * HB_STR];
  __shared__ float xbuf[2][T_LEN];
  __shared__ float outbuf[2][T_LEN];

  const int tid = threadIdx.x;
  const int l   = tid & 63;
  const int w   = tid >> 6;        // wave 0..7
  const int col = l & 15;
  const int q   = l >> 4;
  const int b0  = blockIdx.x * 2;

  // act-cell role (R14-validated)
  const int b  = col & 1;
  const int s  = col >> 1;         // 0..7
  const int r_ = s & 3;
  const int Lc = s >> 2;           // 0: layer1, 1: layer2
  const int u  = 16 * w + 4 * q + r_;

  // ---- A-fragments (one-time; laundered; compiler places in AGPRs) ----
  f32x4n A1[16], A2[16], AI[16];
#pragma unroll
  for (int f = 0; f < 16; ++f) {
    A1[f] = __builtin_bit_cast(f32x4n, wfrag[((0 * 8 + w) * 16 + f) * 64 + l]);
    A2[f] = __builtin_bit_cast(f32x4n, wfrag[((1 * 8 + w) * 16 + f) * 64 + l]);
    AI[f] = __builtin_bit_cast(f32x4n, wfrag[((2 * 8 + w) * 16 + f) * 64 + l]);
  }
#pragma unroll
  for (int f = 0; f < 16; ++f)
    asm volatile("" : "+v"(A1[f]), "+v"(A2[f]), "+v"(AI[f]));

  // ---- per-lane cell constants ----
  float bc[4], wx[4];
#pragma unroll
  for (int g = 0; g < 4; ++g) {
    bc[g] = Lc ? (bih2[g * HID + u] + bhh2[g * HID + u])
               : (bih1[g * HID + u] + bhh1[g * HID + u]);
    wx[g] = Lc ? 0.f : Wih1[g * HID + u];
  }
  const float bo = bout[0];
  float cst = 0.f;

  // ---- wave0: Wout as fp16 pairs matching the Dh fragment layout ----
  // woR[v] holds halves of Wout[32v + q*8 .. +7]
  unsigned int woR[16];
  if (w == 0) {
#pragma unroll
    for (int v = 0; v < 4; ++v)
#pragma unroll
      for (int jj = 0; jj < 4; ++jj) {
        h2_t h;
        h.x = (_Float16)Wout[32 * v + q * 8 + 2 * jj];
        h.y = (_Float16)Wout[32 * v + q * 8 + 2 * jj + 1];
        woR[4 * v + jj] = __builtin_bit_cast(unsigned int, h);
      }
  } else {
#pragma unroll
    for (int v = 0; v < 16; ++v) woR[v] = 0u;
  }

  // ---- init LDS ----
#pragma unroll
  for (int i = 0; i < 4; ++i) {
    int idx = tid + 512 * i;
    int bq  = idx >> 10;
    int ps  = idx & 1023;
    xbuf[bq][ps] = xin[(size_t)(b0 + bq) * T_LEN + ps];
  }
  __syncthreads();

  // ---- prologue: h1(0) (Lc=0); h2 = 0 (Lc=1); parity 0 ----
  if (Lc == 0) {
    float xv = xbuf[b][0];
    float vi = fmaf(wx[0], xv, bc[0]);
    float vg = fmaf(wx[2], xv, bc[2]);
    float vo = fmaf(wx[3], xv, bc[3]);
    float si = fsig(vi), tg = ftanh(vg), so = fsig(vo);
    cst = si * tg;                   // f * c0 = 0
    hB1[0][b * HB_STR + u] = (_Float16)(so * ftanh(cst));
  } else {
    hB2[0][b * HB_STR + u] = (_Float16)0.f;
  }
  __syncthreads();

  const int hb = b * HB_STR + q * 8;   // broadcast B base (halves)

#define LSTM_STEP(P, PN, TT)                                                  \
  {                                                                           \
    f16x8 Bh0 = *reinterpret_cast<const f16x8*>(&hB1[P][hb +  0]);            \
    f16x8 Bh1 = *reinterpret_cast<const f16x8*>(&hB1[P][hb + 32]);            \
    f16x8 Bh2 = *reinterpret_cast<const f16x8*>(&hB1[P][hb + 64]);            \
    f16x8 Bh3 = *reinterpret_cast<const f16x8*>(&hB1[P][hb + 96]);            \
    f16x8 Dh0 = *reinterpret_cast<const f16x8*>(&hB2[P][hb +  0]);            \
    f16x8 Dh1 = *reinterpret_cast<const f16x8*>(&hB2[P][hb + 32]);            \
    f16x8 Dh2 = *reinterpret_cast<const f16x8*>(&hB2[P][hb + 64]);            \
    f16x8 Dh3 = *reinterpret_cast<const f16x8*>(&hB2[P][hb + 96]);            \
    f32x4n C1i = {0,0,0,0}, C1f = {0,0,0,0}, C1g = {0,0,0,0}, C1o = {0,0,0,0};\
    f32x4n Xi = {0,0,0,0}, Xf = {0,0,0,0}, Xg = {0,0,0,0}, Xo = {0,0,0,0};    \
    f32x4n Yi = {0,0,0,0}, Yf = {0,0,0,0}, Yg = {0,0,0,0}, Yo = {0,0,0,0};    \
    C1i = MFMA16(A1[ 0], Bh0, C1i); C1i = MFMA16(A1[ 1], Bh1, C1i);           \
    C1i = MFMA16(A1[ 2], Bh2, C1i); C1i = MFMA16(A1[ 3], Bh3, C1i);           \
    C1f = MFMA16(A1[ 4], Bh0, C1f); C1f = MFMA16(A1[ 5], Bh1, C1f);           \
    C1f = MFMA16(A1[ 6], Bh2, C1f); C1f = MFMA16(A1[ 7], Bh3, C1f);           \
    C1g = MFMA16(A1[ 8], Bh0, C1g); C1g = MFMA16(A1[ 9], Bh1, C1g);           \
    C1g = MFMA16(A1[10], Bh2, C1g); C1g = MFMA16(A1[11], Bh3, C1g);           \
    C1o = MFMA16(A1[12], Bh0, C1o); C1o = MFMA16(A1[13], Bh1, C1o);           \
    C1o = MFMA16(A1[14], Bh2, C1o); C1o = MFMA16(A1[15], Bh3, C1o);           \
    Xi = MFMA16(A2[ 0], Dh0, Xi); Xi = MFMA16(A2[ 1], Dh1, Xi);               \
    Xi = MFMA16(A2[ 2], Dh2, Xi); Xi = MFMA16(A2[ 3], Dh3, Xi);               \
    Xf = MFMA16(A2[ 4], Dh0, Xf); Xf = MFMA16(A2[ 5], Dh1, Xf);               \
    Xf = MFMA16(A2[ 6], Dh2, Xf); Xf = MFMA16(A2[ 7], Dh3, Xf);               \
    Xg = MFMA16(A2[ 8], Dh0, Xg); Xg = MFMA16(A2[ 9], Dh1, Xg);               \
    Xg = MFMA16(A2[10], Dh2, Xg); Xg = MFMA16(A2[11], Dh3, Xg);               \
    Xo = MFMA16(A2[12], Dh0, Xo); Xo = MFMA16(A2[13], Dh1, Xo);               \
    Xo = MFMA16(A2[14], Dh2, Xo); Xo = MFMA16(A2[15], Dh3, Xo);               \
    Yi = MFMA16(AI[ 0], Bh0, Yi); Yi = MFMA16(AI[ 1], Bh1, Yi);               \
    Yi = MFMA16(AI[ 2], Bh2, Yi); Yi = MFMA16(AI[ 3], Bh3, Yi);               \
    Yf = MFMA16(AI[ 4], Bh0, Yf); Yf = MFMA16(AI[ 5], Bh1, Yf);               \
    Yf = MFMA16(AI[ 6], Bh2, Yf); Yf = MFMA16(AI[ 7], Bh3, Yf);               \
    Yg = MFMA16(AI[ 8], Bh0, Yg); Yg = MFMA16(AI[ 9], Bh1, Yg);               \
    Yg = MFMA16(AI[10], Bh2, Yg); Yg = MFMA16(AI[11], Bh3, Yg);               \
    Yo = MFMA16(AI[12], Bh0, Yo); Yo = MFMA16(AI[13], Bh1, Yo);               \
    Yo = MFMA16(AI[14], Bh2, Yo); Yo = MFMA16(AI[15], Bh3, Yo);               \
    if (w == 0 && (TT) > 0) {                                                 \
      uint4 d0 = __builtin_bit_cast(uint4, Dh0);                              \
      uint4 d1 = __builtin_bit_cast(uint4, Dh1);                              \
      uint4 d2 = __builtin_bit_cast(uint4, Dh2);                              \
      uint4 d3 = __builtin_bit_cast(uint4, Dh3);                              \
      float po = 0.f;                                                         \
      po = fdot2u(woR[ 0], d0.x, po); po = fdot2u(woR[ 1], d0.y, po);         \
      po = fdot2u(woR[ 2], d0.z, po); po = fdot2u(woR[ 3], d0.w, po);         \
      po = fdot2u(woR[ 4], d1.x, po); po = fdot2u(woR[ 5], d1.y, po);         \
      po = fdot2u(woR[ 6], d1.z, po); po = fdot2u(woR[ 7], d1.w, po);         \
      po = fdot2u(woR[ 8], d2.x, po); po = fdot2u(woR[ 9], d2.y, po);         \
      po = fdot2u(woR[10], d2.z, po); po = fdot2u(woR[11], d2.w, po);         \
      po = fdot2u(woR[12], d3.x, po); po = fdot2u(woR[13], d3.y, po);         \
      po = fdot2u(woR[14], d3.z, po); po = fdot2u(woR[15], d3.w, po);         \
      po += __shfl_xor(po, 16, 64);                                           \
      po += __shfl_xor(po, 32, 64);                                           \
      if (l < 2) outbuf[l][(TT) - 1] = po;                                    \
    }                                                                         \
    {                                                                         \
      float m_i[4], m_f[4], m_g[4], m_o[4];                                   \
      _Pragma("unroll")                                                       \
      for (int j = 0; j < 4; ++j) {                                           \
        m_i[j] = Lc ? (Xi[j] + Yi[j]) : C1i[j];                               \
        m_f[j] = Lc ? (Xf[j] + Yf[j]) : C1f[j];                               \
        m_g[j] = Lc ? (Xg[j] + Yg[j]) : C1g[j];                               \
        m_o[j] = Lc ? (Xo[j] + Yo[j]) : C1o[j];                               \
      }                                                                       \
      float vi = (r_ == 0) ? m_i[0] : (r_ == 1) ? m_i[1] : (r_ == 2) ? m_i[2] : m_i[3]; \
      float vf = (r_ == 0) ? m_f[0] : (r_ == 1) ? m_f[1] : (r_ == 2) ? m_f[2] : m_f[3]; \
      float vg = (r_ == 0) ? m_g[0] : (r_ == 1) ? m_g[1] : (r_ == 2) ? m_g[2] : m_g[3]; \
      float vo = (r_ == 0) ? m_o[0] : (r_ == 1) ? m_o[1] : (r_ == 2) ? m_o[2] : m_o[3]; \
      int tn = ((TT) + 1) & (T_LEN - 1);                                      \
      float xv = xbuf[b][tn];                                                 \
      vi += fmaf(wx[0], xv, bc[0]);                                           \
      vf += fmaf(wx[1], xv, bc[1]);                                           \
      vg += fmaf(wx[2], xv, bc[2]);                                           \
      vo += fmaf(wx[3], xv, bc[3]);                                           \
      float si = fsig(vi), sf = fsig(vf), tg = ftanh(vg), so = fsig(vo);      \
      cst = fmaf(sf, cst, si * tg);                                           \
      float hv = so * ftanh(cst);                                             \
      _Float16* hp = Lc ? &hB2[PN][0] : &hB1[PN][0];                          \
      hp[b * HB_STR + u] = (_Float16)hv;                                      \
    }                                                                         \
    __syncthreads();                                                          \
  }

  for (int t = 0; t < T_LEN; t += 2) {
    LSTM_STEP(0, 1, t);
    LSTM_STEP(1, 0, t + 1);
  }
#undef LSTM_STEP

  // ---- tail: out(T-1) from final h2 (last act wrote parity 0) ----
  if (w == 0) {
    f16x8 Dh0 = *reinterpret_cast<const f16x8*>(&hB2[0][hb +  0]);
    f16x8 Dh1 = *reinterpret_cast<const f16x8*>(&hB2[0][hb + 32]);
    f16x8 Dh2 = *reinterpret_cast<const f16x8*>(&hB2[0][hb + 64]);
    f16x8 Dh3 = *reinterpret_cast<const f16x8*>(&hB2[0][hb + 96]);
    uint4 d0 = __builtin_bit_cast(uint4, Dh0);
    uint4 d1 = __builtin_bit_cast(uint4, Dh1);
    uint4 d2 = __builtin_bit_cast(uint4, Dh2);
    uint4 d3 = __builtin_bit_cast(uint4, Dh3);
    float po = 0.f;
    po = fdot2u(woR[ 0], d0.x, po); po = fdot2u(woR[ 1], d0.y, po);
    po = fdot2u(woR[ 2], d0.z, po); po = fdot2u(woR[ 3], d0.w, po);
    po = fdot2u(woR[ 4], d1.x, po); po = fdot2u(woR[ 5], d1.y, po);
    po = fdot2u(woR[ 6], d1.z, po); po = fdot2u(woR[ 7], d1.w, po);
    po = fdot2u(woR[ 8], d2.x, po); po = fdot2u(woR[ 9], d2.y, po);
    po = fdot2u(woR[10], d2.z, po); po = fdot2u(woR[11], d2.w, po);
    po = fdot2u(woR[12], d3.x, po); po = fdot2u(woR[13], d3.y, po);
    po = fdot2u(woR[14], d3.z, po); po = fdot2u(woR[15], d3.w, po);
    po += __shfl_xor(po, 16, 64);
    po += __shfl_xor(po, 32, 64);
    if (l < 2) outbuf[l][T_LEN - 1] = po;
  }
  __syncthreads();

  // ---- epilogue: coalesced store ----
#pragma unroll
  for (int i = 0; i < 4; ++i) {
    int idx = tid + 512 * i;
    int bq  = idx >> 10;
    int ps  = idx & 1023;
    outp[(size_t)(b0 + bq) * T_LEN + ps] = outbuf[bq][ps] + bo;
  }
}

// ---------------------------------------------------------------------------
// Fallback (round-1, known-correct fp32 path)
// ---------------------------------------------------------------------------
__global__ void __launch_bounds__(512) transpose_w(
    const float* __restrict__ w1, const float* __restrict__ w2,
    const float* __restrict__ w3, float* __restrict__ o) {
  int m = blockIdx.y;
  const float* src = (m == 0) ? w1 : (m == 1) ? w2 : w3;
  float* dst = o + (size_t)m * G4 * HID;
  int idx = blockIdx.x * 512 + threadIdx.x;
  int j = idx >> 7;
  int k = idx & (HID - 1);
  dst[k * G4 + j] = src[idx];
}

__device__ __forceinline__ float gact(float v, int gt) {
  return (gt == 2) ? ftanh(v) : fsig(v);
}

__device__ __forceinline__ void store_out4(const float4* h2buf, float wo0, float wo1,
                                           float bo, int tid, int b0,
                                           float* __restrict__ outp, int t) {
  float4 ha = h2buf[tid];
  float4 hb = h2buf[tid + 64];
  float p0 = wo0 * ha.x + wo1 * hb.x;
  float p1 = wo0 * ha.y + wo1 * hb.y;
  float p2 = wo0 * ha.z + wo1 * hb.z;
  float p3 = wo0 * ha.w + wo1 * hb.w;
#pragma unroll
  for (int off = 1; off < 64; off <<= 1) {
    p0 += __shfl_xor(p0, off, 64);
    p1 += __shfl_xor(p1, off, 64);
    p2 += __shfl_xor(p2, off, 64);
    p3 += __shfl_xor(p3, off, 64);
  }
  if (tid < BCH) {
    float v = (tid == 0) ? p0 : (tid == 1) ? p1 : (tid == 2) ? p2 : p3;
    outp[(size_t)(b0 + tid) * T_LEN + t] = v + bo;
  }
}

__global__ void __launch_bounds__(512) lstm_fused(
    const float* __restrict__ xin, const float* __restrict__ Wih1,
    const float* __restrict__ bih1, const float* __restrict__ bhh1,
    const float* __restrict__ Whh1, const float* __restrict__ Wih2,
    const float* __restrict__ Whh2, int sk, int sj,
    const float* __restrict__ bih2, const float* __restrict__ bhh2,
    const float* __restrict__ Wout, const float* __restrict__ bout,
    float* __restrict__ outp) {
  __shared__ float4 h1buf[HID];
  __shared__ float4 h2buf[HID];
  __shared__ float4 g1[G4];
  __shared__ float4 g2[G4];
  __shared__ float xb[2][BCH];

  const int tid = threadIdx.x;
  const int b0 = blockIdx.x * BCH;
  const int gt = tid >> 7;

  float bias1 = bih1[tid] + bhh1[tid];
  float bias2 = bih2[tid] + bhh2[tid];
  float wi1 = Wih1[tid];
  float c1_0 = 0.f, c1_1 = 0.f, c1_2 = 0.f, c1_3 = 0.f;
  float c2_0 = 0.f, c2_1 = 0.f, c2_2 = 0.f, c2_3 = 0.f;
  float wo0 = 0.f, wo1 = 0.f, bo = 0.f;
  if (tid < 64) { wo0 = Wout[tid]; wo1 = Wout[tid + 64]; bo = bout[0]; }
  if (tid < HID) {
    h1buf[tid] = make_float4(0.f, 0.f, 0.f, 0.f);
    h2buf[tid] = make_float4(0.f, 0.f, 0.f, 0.f);
  }
  if (tid < BCH) xb[0][tid] = xin[(b0 + tid) * T_LEN];
  __syncthreads();

  const float* wp1  = Whh1 + tid * sj;
  const float* wp2  = Whh2 + tid * sj;
  const float* wpi2 = Wih2 + tid * sj;

  for (int t = 0; t < T_LEN; ++t) {
    float xpref = 0.f;
    if ((tid & ~3) == 128 && (t + 1) < T_LEN)
      xpref = xin[(b0 + (tid & 3)) * T_LEN + t + 1];

    if (tid < 64 && t > 0) store_out4(h2buf, wo0, wo1, bo, tid, b0, outp, t - 1);

    float xv0 = xb[t & 1][0], xv1 = xb[t & 1][1];
    float xv2 = xb[t & 1][2], xv3 = xb[t & 1][3];
    float a10 = fmaf(wi1, xv0, bias1);
    float a11 = fmaf(wi1, xv1, bias1);
    float a12 = fmaf(wi1, xv2, bias1);
    float a13 = fmaf(wi1, xv3, bias1);
    float a20 = bias2, a21 = bias2, a22 = bias2, a23 = bias2;
#pragma unroll 8
    for (int k = 0; k < HID; ++k) {
      float w1 = wp1[k * sk];
      float w2 = wp2[k * sk];
      float4 hv1 = h1buf[k];
      float4 hv2 = h2buf[k];
      a10 = fmaf(w1, hv1.x, a10);
      a11 = fmaf(w1, hv1.y, a11);
      a12 = fmaf(w1, hv1.z, a12);
      a13 = fmaf(w1, hv1.w, a13);
      a20 = fmaf(w2, hv2.x, a20);
      a21 = fmaf(w2, hv2.y, a21);
      a22 = fmaf(w2, hv2.z, a22);
      a23 = fmaf(w2, hv2.w, a23);
    }
    float4 A1v;
    A1v.x = gact(a10, gt); A1v.y = gact(a11, gt);
    A1v.z = gact(a12, gt); A1v.w = gact(a13, gt);
    g1[tid] = A1v;
    __syncthreads();

    if (tid < HID) {
      float4 iv = g1[tid], fv = g1[tid + HID];
      float4 gv = g1[tid + 2 * HID], ov = g1[tid + 3 * HID];
      c1_0 = fmaf(fv.x, c1_0, iv.x * gv.x);
      c1_1 = fmaf(fv.y, c1_1, iv.y * gv.y);
      c1_2 = fmaf(fv.z, c1_2, iv.z * gv.z);
      c1_3 = fmaf(fv.w, c1_3, iv.w * gv.w);
      float4 h;
      h.x = ov.x * ftanh(c1_0);
      h.y = ov.y * ftanh(c1_1);
      h.z = ov.z * ftanh(c1_2);
      h.w = ov.w * ftanh(c1_3);
      h1buf[tid] = h;
    }
    __syncthreads();

#pragma unroll 8
    for (int k = 0; k < HID; ++k) {
      float wv = wpi2[k * sk];
      float4 hv = h1buf[k];
      a20 = fmaf(wv, hv.x, a20);
      a21 = fmaf(wv, hv.y, a21);
      a22 = fmaf(wv, hv.z, a22);
      a23 = fmaf(wv, hv.w, a23);
    }
    float4 A2v;
    A2v.x = gact(a20, gt); A2v.y = gact(a21, gt);
    A2v.z = gact(a22, gt); A2v.w = gact(a23, gt);
    g2[tid] = A2v;
    __syncthreads();

    if (tid < HID) {
      float4 iv = g2[tid], fv = g2[tid + HID];
      float4 gv = g2[tid + 2 * HID], ov = g2[tid + 3 * HID];
      c2_0 = fmaf(fv.x, c2_0, iv.x * gv.x);
      c2_1 = fmaf(fv.y, c2_1, iv.y * gv.y);
      c2_2 = fmaf(fv.z, c2_2, iv.z * gv.z);
      c2_3 = fmaf(fv.w, c2_3, iv.w * gv.w);
      float4 h;
      h.x = ov.x * ftanh(c2_0);
      h.y = ov.y * ftanh(c2_1);
      h.z = ov.z * ftanh(c2_2);
      h.w = ov.w * ftanh(c2_3);
      h2buf[tid] = h;
    } else if ((tid & ~3) == 128 && (t + 1) < T_LEN) {
      xb[(t + 1) & 1][tid & 3] = xpref;
    }
    __syncthreads();
  }
  if (tid < 64) store_out4(h2buf, wo0, wo1, bo, tid, b0, outp, T_LEN - 1);
}

extern "C" void kernel_launch(void* const* d_in, const int* in_sizes, int n_in,
                              void* d_out, int out_size, void* d_ws, size_t ws_size,
                              hipStream_t stream) {
  const float* xin  = (const float*)d_in[0];
  const float* Wih1 = (const float*)d_in[1];
  const float* Whh1 = (const float*)d_in[2];
  const float* bih1 = (const float*)d_in[3];
  const float* bhh1 = (const float*)d_in[4];
  const float* Wih2 = (const float*)d_in[5];
  const float* Whh2 = (const float*)d_in[6];
  const float* bih2 = (const float*)d_in[7];
  const float* bhh2 = (const float*)d_in[8];
  const float* Wout = (const float*)d_in[9];
  const float* bout = (const float*)d_in[10];
  float* outp = (float*)d_out;

  const size_t needFr = (size_t)3 * 8 * 16 * 64 * sizeof(uint4);  // 384 KB
  if (ws_size >= needFr) {
    uint4* wfrag = (uint4*)d_ws;
    pack_frag2<<<96, 256, 0, stream>>>(Whh1, Whh2, Wih2, wfrag);
    lstm_v15<<<256, 512, 0, stream>>>(
        xin, Wih1, bih1, bhh1, wfrag, bih2, bhh2, Wout, bout, outp);
    return;
  }

  // fallback: round-1 fp32 kernel
  size_t need = (size_t)3 * G4 * HID * sizeof(float);
  if (ws_size >= need) {
    float* wt = (float*)d_ws;
    transpose_w<<<dim3(128, 3), 512, 0, stream>>>(Whh1, Wih2, Whh2, wt);
    lstm_fused<<<NG, 512, 0, stream>>>(
        xin, Wih1, bih1, bhh1,
        wt, wt + (size_t)G4 * HID, wt + (size_t)2 * G4 * HID, G4, 1,
        bih2, bhh2, Wout, bout, outp);
  } else {
    lstm_fused<<<NG, 512, 0, stream>>>(
        xin, Wih1, bih1, bhh1,
        Whh1, Wih2, Whh2, 1, HID,
        bih2, bhh2, Wout, bout, outp);
  }
}

// Round 16
// 1754.160 us; speedup vs baseline: 2.0102x; 2.0102x over previous
//
#include <hip/hip_runtime.h>

#define T_LEN 1024
#define HID   128
#define G4    512
#define NG    128      // fallback WGs
#define BCH   4        // fallback batch/WG
#define HB_STR 136     // halves per h buffer row (padded)

typedef _Float16 h2_t   __attribute__((ext_vector_type(2)));
typedef _Float16 f16x8  __attribute__((ext_vector_type(8)));
typedef float    f32x4n __attribute__((ext_vector_type(4)));

__device__ __forceinline__ float fsig(float v) {
  return __builtin_amdgcn_rcpf(1.0f + __expf(-v));
}
__device__ __forceinline__ float ftanh(float v) {
  float a = fabsf(v);
  float e = __expf(-2.0f * a);
  float t = (1.0f - e) * __builtin_amdgcn_rcpf(1.0f + e);
  return copysignf(t, v);
}
__device__ __forceinline__ float fdot2u(unsigned int a, unsigned int b, float c) {
  union { unsigned int u; h2_t h; } ca, cb;
  ca.u = a; cb.u = b;
  return __builtin_amdgcn_fdot2(ca.h, cb.h, c, false);
}

#define MFMA16(A, B, C) __builtin_amdgcn_mfma_f32_16x16x32_f16( \
    __builtin_bit_cast(f16x8, (A)), (B), (C), 0, 0, 0)

// ---------------------------------------------------------------------------
// Pack fp32 weights into MFMA A-fragments (fp16), gate-tiled per wave
// (identical to R5..R15 — validated): dst[((m*8+w)*16 + g*4+kt)*64 + l] =
// 8 halves of row = g*128 + 16w + (l&15), k = 32*kt + (l>>4)*8.
// m: 0=Whh1, 1=Whh2, 2=Wih2.
// ---------------------------------------------------------------------------
__global__ void __launch_bounds__(256) pack_frag2(
    const float* __restrict__ wa, const float* __restrict__ wb,
    const float* __restrict__ wc, uint4* __restrict__ dst) {
  int idx = blockIdx.x * 256 + threadIdx.x;   // 0..24575
  int l = idx & 63;
  int f = (idx >> 6) & 15;
  int w = (idx >> 10) & 7;
  int m = idx >> 13;
  const float* src = (m == 0) ? wa : (m == 1) ? wb : wc;
  int row = (f >> 2) * HID + 16 * w + (l & 15);
  int k0  = 32 * (f & 3) + (l >> 4) * 8;
  const float* s = src + (size_t)row * HID + k0;
  unsigned int r[4];
#pragma unroll
  for (int qq = 0; qq < 4; ++qq) {
    h2_t h;
    h.x = (_Float16)s[2 * qq];
    h.y = (_Float16)s[2 * qq + 1];
    r[qq] = __builtin_bit_cast(unsigned int, h);
  }
  dst[idx] = make_uint4(r[0], r[1], r[2], r[3]);
}

// ---------------------------------------------------------------------------
// R16 = R14 (in-lane act, 1 barrier/step, 256 WGs x 512 thr, 2 batches/WG)
// with ONE change: the out-reduction (5 shfl_xor on all 8 waves) is replaced
// by R10's wave-0 fdot2 out-dot (wo read from LDS woh, Dh fragments wave 0
// already loads, 2 shfl on wave 0 only). Register-neutral vs R14.
// ---------------------------------------------------------------------------
__global__ void __launch_bounds__(512, 2) lstm_v16(
    const float* __restrict__ xin, const float* __restrict__ Wih1,
    const float* __restrict__ bih1, const float* __restrict__ bhh1,
    const uint4* __restrict__ wfrag,
    const float* __restrict__ bih2, const float* __restrict__ bhh2,
    const float* __restrict__ Wout, const float* __restrict__ bout,
    float* __restrict__ outp)
{
  __shared__ __align__(16) _Float16 hB1[2][2 * HB_STR];  // [parity][batch][unit]
  __shared__ __align__(16) _Float16 hB2[2][2 * HB_STR];
  __shared__ __align__(16) _Float16 woh[HID];
  __shared__ float xbuf[2][T_LEN];
  __shared__ float outbuf[2][T_LEN];

  const int tid = threadIdx.x;
  const int l   = tid & 63;
  const int w   = tid >> 6;        // wave 0..7
  const int col = l & 15;
  const int q   = l >> 4;
  const int b0  = blockIdx.x * 2;

  // act-cell role (R14-validated)
  const int b  = col & 1;
  const int s  = col >> 1;         // 0..7
  const int r_ = s & 3;
  const int Lc = s >> 2;           // 0: layer1, 1: layer2
  const int u  = 16 * w + 4 * q + r_;

  // ---- A-fragments (one-time; laundered; compiler places in AGPRs) ----
  f32x4n A1[16], A2[16], AI[16];
#pragma unroll
  for (int f = 0; f < 16; ++f) {
    A1[f] = __builtin_bit_cast(f32x4n, wfrag[((0 * 8 + w) * 16 + f) * 64 + l]);
    A2[f] = __builtin_bit_cast(f32x4n, wfrag[((1 * 8 + w) * 16 + f) * 64 + l]);
    AI[f] = __builtin_bit_cast(f32x4n, wfrag[((2 * 8 + w) * 16 + f) * 64 + l]);
  }
#pragma unroll
  for (int f = 0; f < 16; ++f)
    asm volatile("" : "+v"(A1[f]), "+v"(A2[f]), "+v"(AI[f]));

  // ---- per-lane cell constants ----
  float bc[4], wx[4];
#pragma unroll
  for (int g = 0; g < 4; ++g) {
    bc[g] = Lc ? (bih2[g * HID + u] + bhh2[g * HID + u])
               : (bih1[g * HID + u] + bhh1[g * HID + u]);
    wx[g] = Lc ? 0.f : Wih1[g * HID + u];
  }
  const float bo = bout[0];
  float cst = 0.f;

  // ---- init LDS ----
  if (tid < HID) woh[tid] = (_Float16)Wout[tid];
#pragma unroll
  for (int i = 0; i < 4; ++i) {
    int idx = tid + 512 * i;
    int bq  = idx >> 10;
    int ps  = idx & 1023;
    xbuf[bq][ps] = xin[(size_t)(b0 + bq) * T_LEN + ps];
  }
  __syncthreads();

  // ---- prologue: h1(0) (Lc=0); h2 = 0 (Lc=1); parity 0 ----
  if (Lc == 0) {
    float xv = xbuf[b][0];
    float vi = fmaf(wx[0], xv, bc[0]);
    float vg = fmaf(wx[2], xv, bc[2]);
    float vo = fmaf(wx[3], xv, bc[3]);
    float si = fsig(vi), tg = ftanh(vg), so = fsig(vo);
    cst = si * tg;                   // f * c0 = 0
    hB1[0][b * HB_STR + u] = (_Float16)(so * ftanh(cst));
  } else {
    hB2[0][b * HB_STR + u] = (_Float16)0.f;
  }
  __syncthreads();

  const int hb = b * HB_STR + q * 8;   // broadcast B base (halves)

  for (int t = 0; t < T_LEN; ++t) {
    const int p  = t & 1;
    const int pn = p ^ 1;

    // ================= M: 48 MFMA on h1(t) (Bh) and h2(t-1) (Dh) ==========
    f16x8 Bh0 = *reinterpret_cast<const f16x8*>(&hB1[p][hb +  0]);
    f16x8 Bh1 = *reinterpret_cast<const f16x8*>(&hB1[p][hb + 32]);
    f16x8 Bh2 = *reinterpret_cast<const f16x8*>(&hB1[p][hb + 64]);
    f16x8 Bh3 = *reinterpret_cast<const f16x8*>(&hB1[p][hb + 96]);
    f16x8 Dh0 = *reinterpret_cast<const f16x8*>(&hB2[p][hb +  0]);
    f16x8 Dh1 = *reinterpret_cast<const f16x8*>(&hB2[p][hb + 32]);
    f16x8 Dh2 = *reinterpret_cast<const f16x8*>(&hB2[p][hb + 64]);
    f16x8 Dh3 = *reinterpret_cast<const f16x8*>(&hB2[p][hb + 96]);

    f32x4n C1i = {0,0,0,0}, C1f = {0,0,0,0}, C1g = {0,0,0,0}, C1o = {0,0,0,0};
    f32x4n C2i = {0,0,0,0}, C2f = {0,0,0,0}, C2g = {0,0,0,0}, C2o = {0,0,0,0};

    C1i = MFMA16(A1[ 0], Bh0, C1i); C1i = MFMA16(A1[ 1], Bh1, C1i);
    C1i = MFMA16(A1[ 2], Bh2, C1i); C1i = MFMA16(A1[ 3], Bh3, C1i);
    C1f = MFMA16(A1[ 4], Bh0, C1f); C1f = MFMA16(A1[ 5], Bh1, C1f);
    C1f = MFMA16(A1[ 6], Bh2, C1f); C1f = MFMA16(A1[ 7], Bh3, C1f);
    C1g = MFMA16(A1[ 8], Bh0, C1g); C1g = MFMA16(A1[ 9], Bh1, C1g);
    C1g = MFMA16(A1[10], Bh2, C1g); C1g = MFMA16(A1[11], Bh3, C1g);
    C1o = MFMA16(A1[12], Bh0, C1o); C1o = MFMA16(A1[13], Bh1, C1o);
    C1o = MFMA16(A1[14], Bh2, C1o); C1o = MFMA16(A1[15], Bh3, C1o);

    C2i = MFMA16(A2[ 0], Dh0, C2i); C2i = MFMA16(A2[ 1], Dh1, C2i);
    C2i = MFMA16(A2[ 2], Dh2, C2i); C2i = MFMA16(A2[ 3], Dh3, C2i);
    C2f = MFMA16(A2[ 4], Dh0, C2f); C2f = MFMA16(A2[ 5], Dh1, C2f);
    C2f = MFMA16(A2[ 6], Dh2, C2f); C2f = MFMA16(A2[ 7], Dh3, C2f);
    C2g = MFMA16(A2[ 8], Dh0, C2g); C2g = MFMA16(A2[ 9], Dh1, C2g);
    C2g = MFMA16(A2[10], Dh2, C2g); C2g = MFMA16(A2[11], Dh3, C2g);
    C2o = MFMA16(A2[12], Dh0, C2o); C2o = MFMA16(A2[13], Dh1, C2o);
    C2o = MFMA16(A2[14], Dh2, C2o); C2o = MFMA16(A2[15], Dh3, C2o);

    C2i = MFMA16(AI[ 0], Bh0, C2i); C2i = MFMA16(AI[ 1], Bh1, C2i);
    C2i = MFMA16(AI[ 2], Bh2, C2i); C2i = MFMA16(AI[ 3], Bh3, C2i);
    C2f = MFMA16(AI[ 4], Bh0, C2f); C2f = MFMA16(AI[ 5], Bh1, C2f);
    C2f = MFMA16(AI[ 6], Bh2, C2f); C2f = MFMA16(AI[ 7], Bh3, C2f);
    C2g = MFMA16(AI[ 8], Bh0, C2g); C2g = MFMA16(AI[ 9], Bh1, C2g);
    C2g = MFMA16(AI[10], Bh2, C2g); C2g = MFMA16(AI[11], Bh3, C2g);
    C2o = MFMA16(AI[12], Bh0, C2o); C2o = MFMA16(AI[13], Bh1, C2o);
    C2o = MFMA16(AI[14], Bh2, C2o); C2o = MFMA16(AI[15], Bh3, C2o);

    // out(t-1) = wo . h2(t-1): wave 0 only, from the Dh fragments it already
    // has (R10-validated). 4 LDS reads + 16 fdot2 + 2 shfl, wave 0 only.
    if (w == 0 && t > 0) {
      f16x8 W0 = *reinterpret_cast<const f16x8*>(&woh[q * 8 +  0]);
      f16x8 W1 = *reinterpret_cast<const f16x8*>(&woh[q * 8 + 32]);
      f16x8 W2 = *reinterpret_cast<const f16x8*>(&woh[q * 8 + 64]);
      f16x8 W3 = *reinterpret_cast<const f16x8*>(&woh[q * 8 + 96]);
      uint4 d0 = __builtin_bit_cast(uint4, Dh0), w0_ = __builtin_bit_cast(uint4, W0);
      uint4 d1 = __builtin_bit_cast(uint4, Dh1), w1_ = __builtin_bit_cast(uint4, W1);
      uint4 d2 = __builtin_bit_cast(uint4, Dh2), w2_ = __builtin_bit_cast(uint4, W2);
      uint4 d3 = __builtin_bit_cast(uint4, Dh3), w3_ = __builtin_bit_cast(uint4, W3);
      float po = 0.f;
      po = fdot2u(w0_.x, d0.x, po); po = fdot2u(w0_.y, d0.y, po);
      po = fdot2u(w0_.z, d0.z, po); po = fdot2u(w0_.w, d0.w, po);
      po = fdot2u(w1_.x, d1.x, po); po = fdot2u(w1_.y, d1.y, po);
      po = fdot2u(w1_.z, d1.z, po); po = fdot2u(w1_.w, d1.w, po);
      po = fdot2u(w2_.x, d2.x, po); po = fdot2u(w2_.y, d2.y, po);
      po = fdot2u(w2_.z, d2.z, po); po = fdot2u(w2_.w, d2.w, po);
      po = fdot2u(w3_.x, d3.x, po); po = fdot2u(w3_.y, d3.y, po);
      po = fdot2u(w3_.z, d3.z, po); po = fdot2u(w3_.w, d3.w, po);
      po += __shfl_xor(po, 16, 64);
      po += __shfl_xor(po, 32, 64);
      if (l < 2) outbuf[l][t - 1] = po;
    }

    // ================= act: one LSTM cell per lane, in-register ===========
    {
      float Gi[4], Gf[4], Gg[4], Go[4];
#pragma unroll
      for (int j = 0; j < 4; ++j) {
        Gi[j] = Lc ? C2i[j] : C1i[j];
        Gf[j] = Lc ? C2f[j] : C1f[j];
        Gg[j] = Lc ? C2g[j] : C1g[j];
        Go[j] = Lc ? C2o[j] : C1o[j];
      }
      float vi = (r_ == 0) ? Gi[0] : (r_ == 1) ? Gi[1] : (r_ == 2) ? Gi[2] : Gi[3];
      float vf = (r_ == 0) ? Gf[0] : (r_ == 1) ? Gf[1] : (r_ == 2) ? Gf[2] : Gf[3];
      float vg = (r_ == 0) ? Gg[0] : (r_ == 1) ? Gg[1] : (r_ == 2) ? Gg[2] : Gg[3];
      float vo = (r_ == 0) ? Go[0] : (r_ == 1) ? Go[1] : (r_ == 2) ? Go[2] : Go[3];

      int tn = (t + 1) & (T_LEN - 1);
      float xv = xbuf[b][tn];           // only matters for Lc==0 (wx==0 else)
      vi += fmaf(wx[0], xv, bc[0]);
      vf += fmaf(wx[1], xv, bc[1]);
      vg += fmaf(wx[2], xv, bc[2]);
      vo += fmaf(wx[3], xv, bc[3]);
      float si = fsig(vi), sf = fsig(vf), tg = ftanh(vg), so = fsig(vo);
      cst = fmaf(sf, cst, si * tg);
      float hv = so * ftanh(cst);
      _Float16* hp = Lc ? &hB2[pn][0] : &hB1[pn][0];
      hp[b * HB_STR + u] = (_Float16)hv;
    }
    __syncthreads();   // ---- the ONLY barrier ----
  }

  // ---- tail: out(T-1) from final h2 (last act wrote parity 0) ----
  if (w == 0) {
    f16x8 Dh0 = *reinterpret_cast<const f16x8*>(&hB2[0][hb +  0]);
    f16x8 Dh1 = *reinterpret_cast<const f16x8*>(&hB2[0][hb + 32]);
    f16x8 Dh2 = *reinterpret_cast<const f16x8*>(&hB2[0][hb + 64]);
    f16x8 Dh3 = *reinterpret_cast<const f16x8*>(&hB2[0][hb + 96]);
    f16x8 W0 = *reinterpret_cast<const f16x8*>(&woh[q * 8 +  0]);
    f16x8 W1 = *reinterpret_cast<const f16x8*>(&woh[q * 8 + 32]);
    f16x8 W2 = *reinterpret_cast<const f16x8*>(&woh[q * 8 + 64]);
    f16x8 W3 = *reinterpret_cast<const f16x8*>(&woh[q * 8 + 96]);
    uint4 d0 = __builtin_bit_cast(uint4, Dh0), w0_ = __builtin_bit_cast(uint4, W0);
    uint4 d1 = __builtin_bit_cast(uint4, Dh1), w1_ = __builtin_bit_cast(uint4, W1);
    uint4 d2 = __builtin_bit_cast(uint4, Dh2), w2_ = __builtin_bit_cast(uint4, W2);
    uint4 d3 = __builtin_bit_cast(uint4, Dh3), w3_ = __builtin_bit_cast(uint4, W3);
    float po = 0.f;
    po = fdot2u(w0_.x, d0.x, po); po = fdot2u(w0_.y, d0.y, po);
    po = fdot2u(w0_.z, d0.z, po); po = fdot2u(w0_.w, d0.w, po);
    po = fdot2u(w1_.x, d1.x, po); po = fdot2u(w1_.y, d1.y, po);
    po = fdot2u(w1_.z, d1.z, po); po = fdot2u(w1_.w, d1.w, po);
    po = fdot2u(w2_.x, d2.x, po); po = fdot2u(w2_.y, d2.y, po);
    po = fdot2u(w2_.z, d2.z, po); po = fdot2u(w2_.w, d2.w, po);
    po = fdot2u(w3_.x, d3.x, po); po = fdot2u(w3_.y, d3.y, po);
    po = fdot2u(w3_.z, d3.z, po); po = fdot2u(w3_.w, d3.w, po);
    po += __shfl_xor(po, 16, 64);
    po += __shfl_xor(po, 32, 64);
    if (l < 2) outbuf[l][T_LEN - 1] = po;
  }
  __syncthreads();

  // ---- epilogue: coalesced store ----
#pragma unroll
  for (int i = 0; i < 4; ++i) {
    int idx = tid + 512 * i;
    int bq  = idx >> 10;
    int ps  = idx & 1023;
    outp[(size_t)(b0 + bq) * T_LEN + ps] = outbuf[bq][ps] + bo;
  }
}

// ---------------------------------------------------------------------------
// Fallback (round-1, known-correct fp32 path)
// ---------------------------------------------------------------------------
__global__ void __launch_bounds__(512) transpose_w(
    const float* __restrict__ w1, const float* __restrict__ w2,
    const float* __restrict__ w3, float* __restrict__ o) {
  int m = blockIdx.y;
  const float* src = (m == 0) ? w1 : (m == 1) ? w2 : w3;
  float* dst = o + (size_t)m * G4 * HID;
  int idx = blockIdx.x * 512 + threadIdx.x;
  int j = idx >> 7;
  int k = idx & (HID - 1);
  dst[k * G4 + j] = src[idx];
}

__device__ __forceinline__ float gact(float v, int gt) {
  return (gt == 2) ? ftanh(v) : fsig(v);
}

__device__ __forceinline__ void store_out4(const float4* h2buf, float wo0, float wo1,
                                           float bo, int tid, int b0,
                                           float* __restrict__ outp, int t) {
  float4 ha = h2buf[tid];
  float4 hb = h2buf[tid + 64];
  float p0 = wo0 * ha.x + wo1 * hb.x;
  float p1 = wo0 * ha.y + wo1 * hb.y;
  float p2 = wo0 * ha.z + wo1 * hb.z;
  float p3 = wo0 * ha.w + wo1 * hb.w;
#pragma unroll
  for (int off = 1; off < 64; off <<= 1) {
    p0 += __shfl_xor(p0, off, 64);
    p1 += __shfl_xor(p1, off, 64);
    p2 += __shfl_xor(p2, off, 64);
    p3 += __shfl_xor(p3, off, 64);
  }
  if (tid < BCH) {
    float v = (tid == 0) ? p0 : (tid == 1) ? p1 : (tid == 2) ? p2 : p3;
    outp[(size_t)(b0 + tid) * T_LEN + t] = v + bo;
  }
}

__global__ void __launch_bounds__(512) lstm_fused(
    const float* __restrict__ xin, const float* __restrict__ Wih1,
    const float* __restrict__ bih1, const float* __restrict__ bhh1,
    const float* __restrict__ Whh1, const float* __restrict__ Wih2,
    const float* __restrict__ Whh2, int sk, int sj,
    const float* __restrict__ bih2, const float* __restrict__ bhh2,
    const float* __restrict__ Wout, const float* __restrict__ bout,
    float* __restrict__ outp) {
  __shared__ float4 h1buf[HID];
  __shared__ float4 h2buf[HID];
  __shared__ float4 g1[G4];
  __shared__ float4 g2[G4];
  __shared__ float xb[2][BCH];

  const int tid = threadIdx.x;
  const int b0 = blockIdx.x * BCH;
  const int gt = tid >> 7;

  float bias1 = bih1[tid] + bhh1[tid];
  float bias2 = bih2[tid] + bhh2[tid];
  float wi1 = Wih1[tid];
  float c1_0 = 0.f, c1_1 = 0.f, c1_2 = 0.f, c1_3 = 0.f;
  float c2_0 = 0.f, c2_1 = 0.f, c2_2 = 0.f, c2_3 = 0.f;
  float wo0 = 0.f, wo1 = 0.f, bo = 0.f;
  if (tid < 64) { wo0 = Wout[tid]; wo1 = Wout[tid + 64]; bo = bout[0]; }
  if (tid < HID) {
    h1buf[tid] = make_float4(0.f, 0.f, 0.f, 0.f);
    h2buf[tid] = make_float4(0.f, 0.f, 0.f, 0.f);
  }
  if (tid < BCH) xb[0][tid] = xin[(b0 + tid) * T_LEN];
  __syncthreads();

  const float* wp1  = Whh1 + tid * sj;
  const float* wp2  = Whh2 + tid * sj;
  const float* wpi2 = Wih2 + tid * sj;

  for (int t = 0; t < T_LEN; ++t) {
    float xpref = 0.f;
    if ((tid & ~3) == 128 && (t + 1) < T_LEN)
      xpref = xin[(b0 + (tid & 3)) * T_LEN + t + 1];

    if (tid < 64 && t > 0) store_out4(h2buf, wo0, wo1, bo, tid, b0, outp, t - 1);

    float xv0 = xb[t & 1][0], xv1 = xb[t & 1][1];
    float xv2 = xb[t & 1][2], xv3 = xb[t & 1][3];
    float a10 = fmaf(wi1, xv0, bias1);
    float a11 = fmaf(wi1, xv1, bias1);
    float a12 = fmaf(wi1, xv2, bias1);
    float a13 = fmaf(wi1, xv3, bias1);
    float a20 = bias2, a21 = bias2, a22 = bias2, a23 = bias2;
#pragma unroll 8
    for (int k = 0; k < HID; ++k) {
      float w1 = wp1[k * sk];
      float w2 = wp2[k * sk];
      float4 hv1 = h1buf[k];
      float4 hv2 = h2buf[k];
      a10 = fmaf(w1, hv1.x, a10);
      a11 = fmaf(w1, hv1.y, a11);
      a12 = fmaf(w1, hv1.z, a12);
      a13 = fmaf(w1, hv1.w, a13);
      a20 = fmaf(w2, hv2.x, a20);
      a21 = fmaf(w2, hv2.y, a21);
      a22 = fmaf(w2, hv2.z, a22);
      a23 = fmaf(w2, hv2.w, a23);
    }
    float4 A1v;
    A1v.x = gact(a10, gt); A1v.y = gact(a11, gt);
    A1v.z = gact(a12, gt); A1v.w = gact(a13, gt);
    g1[tid] = A1v;
    __syncthreads();

    if (tid < HID) {
      float4 iv = g1[tid], fv = g1[tid + HID];
      float4 gv = g1[tid + 2 * HID], ov = g1[tid + 3 * HID];
      c1_0 = fmaf(fv.x, c1_0, iv.x * gv.x);
      c1_1 = fmaf(fv.y, c1_1, iv.y * gv.y);
      c1_2 = fmaf(fv.z, c1_2, iv.z * gv.z);
      c1_3 = fmaf(fv.w, c1_3, iv.w * gv.w);
      float4 h;
      h.x = ov.x * ftanh(c1_0);
      h.y = ov.y * ftanh(c1_1);
      h.z = ov.z * ftanh(c1_2);
      h.w = ov.w * ftanh(c1_3);
      h1buf[tid] = h;
    }
    __syncthreads();

#pragma unroll 8
    for (int k = 0; k < HID; ++k) {
      float wv = wpi2[k * sk];
      float4 hv = h1buf[k];
      a20 = fmaf(wv, hv.x, a20);
      a21 = fmaf(wv, hv.y, a21);
      a22 = fmaf(wv, hv.z, a22);
      a23 = fmaf(wv, hv.w, a23);
    }
    float4 A2v;
    A2v.x = gact(a20, gt); A2v.y = gact(a21, gt);
    A2v.z = gact(a22, gt); A2v.w = gact(a23, gt);
    g2[tid] = A2v;
    __syncthreads();

    if (tid < HID) {
      float4 iv = g2[tid], fv = g2[tid + HID];
      float4 gv = g2[tid + 2 * HID], ov = g2[tid + 3 * HID];
      c2_0 = fmaf(fv.x, c2_0, iv.x * gv.x);
      c2_1 = fmaf(fv.y, c2_1, iv.y * gv.y);
      c2_2 = fmaf(fv.z, c2_2, iv.z * gv.z);
      c2_3 = fmaf(fv.w, c2_3, iv.w * gv.w);
      float4 h;
      h.x = ov.x * ftanh(c2_0);
      h.y = ov.y * ftanh(c2_1);
      h.z = ov.z * ftanh(c2_2);
      h.w = ov.w * ftanh(c2_3);
      h2buf[tid] = h;
    } else if ((tid & ~3) == 128 && (t + 1) < T_LEN) {
      xb[(t + 1) & 1][tid & 3] = xpref;
    }
    __syncthreads();
  }
  if (tid < 64) store_out4(h2buf, wo0, wo1, bo, tid, b0, outp, T_LEN - 1);
}

extern "C" void kernel_launch(void* const* d_in, const int* in_sizes, int n_in,
                              void* d_out, int out_size, void* d_ws, size_t ws_size,
                              hipStream_t stream) {
  const float* xin  = (const float*)d_in[0];
  const float* Wih1 = (const float*)d_in[1];
  const float* Whh1 = (const float*)d_in[2];
  const float* bih1 = (const float*)d_in[3];
  const float* bhh1 = (const float*)d_in[4];
  const float* Wih2 = (const float*)d_in[5];
  const float* Whh2 = (const float*)d_in[6];
  const float* bih2 = (const float*)d_in[7];
  const float* bhh2 = (const float*)d_in[8];
  const float* Wout = (const float*)d_in[9];
  const float* bout = (const float*)d_in[10];
  float* outp = (float*)d_out;

  const size_t needFr = (size_t)3 * 8 * 16 * 64 * sizeof(uint4);  // 384 KB
  if (ws_size >= needFr) {
    uint4* wfrag = (uint4*)d_ws;
    pack_frag2<<<96, 256, 0, stream>>>(Whh1, Whh2, Wih2, wfrag);
    lstm_v16<<<256, 512, 0, stream>>>(
        xin, Wih1, bih1, bhh1, wfrag, bih2, bhh2, Wout, bout, outp);
    return;
  }

  // fallback: round-1 fp32 kernel
  size_t need = (size_t)3 * G4 * HID * sizeof(float);
  if (ws_size >= need) {
    float* wt = (float*)d_ws;
    transpose_w<<<dim3(128, 3), 512, 0, stream>>>(Whh1, Wih2, Whh2, wt);
    lstm_fused<<<NG, 512, 0, stream>>>(
        xin, Wih1, bih1, bhh1,
        wt, wt + (size_t)G4 * HID, wt + (size_t)2 * G4 * HID, G4, 1,
        bih2, bhh2, Wout, bout, outp);
  } else {
    lstm_fused<<<NG, 512, 0, stream>>>(
        xin, Wih1, bih1, bhh1,
        Whh1, Wih2, Whh2, 1, HID,
        bih2, bhh2, Wout, bout, outp);
  }
}

// Round 17
// 1370.938 us; speedup vs baseline: 2.5721x; 1.2795x over previous
//
#include <hip/hip_runtime.h>

#define T_LEN 1024
#define HID   128
#define G4    512
#define NG    128      // fallback WGs
#define BCH   4        // fallback batch/WG
#define HB_STR 136     // halves per h buffer row (padded)

typedef _Float16 h2_t   __attribute__((ext_vector_type(2)));
typedef _Float16 f16x8  __attribute__((ext_vector_type(8)));
typedef float    f32x4n __attribute__((ext_vector_type(4)));

__device__ __forceinline__ float fsig(float v) {
  return __builtin_amdgcn_rcpf(1.0f + __expf(-v));
}
__device__ __forceinline__ float ftanh(float v) {
  float a = fabsf(v);
  float e = __expf(-2.0f * a);
  float t = (1.0f - e) * __builtin_amdgcn_rcpf(1.0f + e);
  return copysignf(t, v);
}

#define MFMA16(A, B, C) __builtin_amdgcn_mfma_f32_16x16x32_f16( \
    __builtin_bit_cast(f16x8, (A)), (B), (C), 0, 0, 0)

// ---------------------------------------------------------------------------
// Pack fp32 weights into MFMA A-fragments (fp16), gate-tiled per wave
// (identical to R5..R16 — validated): dst[((m*8+w)*16 + g*4+kt)*64 + l] =
// 8 halves of row = g*128 + 16w + (l&15), k = 32*kt + (l>>4)*8.
// m: 0=Whh1, 1=Whh2, 2=Wih2.
// ---------------------------------------------------------------------------
__global__ void __launch_bounds__(256) pack_frag2(
    const float* __restrict__ wa, const float* __restrict__ wb,
    const float* __restrict__ wc, uint4* __restrict__ dst) {
  int idx = blockIdx.x * 256 + threadIdx.x;   // 0..24575
  int l = idx & 63;
  int f = (idx >> 6) & 15;
  int w = (idx >> 10) & 7;
  int m = idx >> 13;
  const float* src = (m == 0) ? wa : (m == 1) ? wb : wc;
  int row = (f >> 2) * HID + 16 * w + (l & 15);
  int k0  = 32 * (f & 3) + (l >> 4) * 8;
  const float* s = src + (size_t)row * HID + k0;
  unsigned int r[4];
#pragma unroll
  for (int qq = 0; qq < 4; ++qq) {
    h2_t h;
    h.x = (_Float16)s[2 * qq];
    h.y = (_Float16)s[2 * qq + 1];
    r[qq] = __builtin_bit_cast(unsigned int, h);
  }
  dst[idx] = make_uint4(r[0], r[1], r[2], r[3]);
}

// ---------------------------------------------------------------------------
// R17 = R14 (in-lane act, 1 barrier/step, all-wave 5-shfl out-reduce, 256 WGs
// x 512 thr, 2 batches/WG) with ONE register-neutral change: the 48 MFMAs are
// issued kt-OUTER (all 12 independent accumulator chains per kt) so dependent
// MFMAs are separated by 11 independent issues — hides the ~16cy dependent
// latency that chain-ordered issue exposed (~15cy effective interval in R14).
// ---------------------------------------------------------------------------
__global__ void __launch_bounds__(512, 2) lstm_v17(
    const float* __restrict__ xin, const float* __restrict__ Wih1,
    const float* __restrict__ bih1, const float* __restrict__ bhh1,
    const uint4* __restrict__ wfrag,
    const float* __restrict__ bih2, const float* __restrict__ bhh2,
    const float* __restrict__ Wout, const float* __restrict__ bout,
    float* __restrict__ outp)
{
  __shared__ __align__(16) _Float16 hB1[2][2 * HB_STR];  // [parity][batch][unit]
  __shared__ __align__(16) _Float16 hB2[2][2 * HB_STR];
  __shared__ float prt[2][8][2];
  __shared__ float xbuf[2][T_LEN];
  __shared__ float outbuf[2][T_LEN];

  const int tid = threadIdx.x;
  const int l   = tid & 63;
  const int w   = tid >> 6;        // wave 0..7
  const int col = l & 15;
  const int q   = l >> 4;
  const int b0  = blockIdx.x * 2;

  // act-cell role (R14-validated)
  const int b  = col & 1;
  const int s  = col >> 1;         // 0..7
  const int r_ = s & 3;
  const int Lc = s >> 2;           // 0: layer1, 1: layer2
  const int u  = 16 * w + 4 * q + r_;

  // ---- A-fragments (one-time; laundered; compiler places in AGPRs) ----
  f32x4n A1[16], A2[16], AI[16];
#pragma unroll
  for (int f = 0; f < 16; ++f) {
    A1[f] = __builtin_bit_cast(f32x4n, wfrag[((0 * 8 + w) * 16 + f) * 64 + l]);
    A2[f] = __builtin_bit_cast(f32x4n, wfrag[((1 * 8 + w) * 16 + f) * 64 + l]);
    AI[f] = __builtin_bit_cast(f32x4n, wfrag[((2 * 8 + w) * 16 + f) * 64 + l]);
  }
#pragma unroll
  for (int f = 0; f < 16; ++f)
    asm volatile("" : "+v"(A1[f]), "+v"(A2[f]), "+v"(AI[f]));

  // ---- per-lane cell constants ----
  float bc[4], wx[4];
#pragma unroll
  for (int g = 0; g < 4; ++g) {
    bc[g] = Lc ? (bih2[g * HID + u] + bhh2[g * HID + u])
               : (bih1[g * HID + u] + bhh1[g * HID + u]);
    wx[g] = Lc ? 0.f : Wih1[g * HID + u];
  }
  const float wo = Wout[u];        // used only by Lc==1 lanes
  const float bo = bout[0];
  float cst = 0.f;

  // ---- init LDS ----
#pragma unroll
  for (int i = 0; i < 4; ++i) {
    int idx = tid + 512 * i;
    int bq  = idx >> 10;
    int ps  = idx & 1023;
    xbuf[bq][ps] = xin[(size_t)(b0 + bq) * T_LEN + ps];
  }
  if (l < 2) { prt[0][w][l] = 0.f; prt[1][w][l] = 0.f; }
  __syncthreads();

  // ---- prologue: h1(0) (Lc=0); h2 = 0 (Lc=1); parity 0 ----
  if (Lc == 0) {
    float xv = xbuf[b][0];
    float vi = fmaf(wx[0], xv, bc[0]);
    float vg = fmaf(wx[2], xv, bc[2]);
    float vo = fmaf(wx[3], xv, bc[3]);
    float si = fsig(vi), tg = ftanh(vg), so = fsig(vo);
    cst = si * tg;                   // f * c0 = 0
    hB1[0][b * HB_STR + u] = (_Float16)(so * ftanh(cst));
  } else {
    hB2[0][b * HB_STR + u] = (_Float16)0.f;
  }
  __syncthreads();

  const int hb = b * HB_STR + q * 8;   // broadcast B base (halves)

  for (int t = 0; t < T_LEN; ++t) {
    const int p  = t & 1;
    const int pn = p ^ 1;

    // ================= M: 48 MFMA, kt-OUTER issue order =================
    f16x8 Bh0 = *reinterpret_cast<const f16x8*>(&hB1[p][hb +  0]);
    f16x8 Bh1 = *reinterpret_cast<const f16x8*>(&hB1[p][hb + 32]);
    f16x8 Bh2 = *reinterpret_cast<const f16x8*>(&hB1[p][hb + 64]);
    f16x8 Bh3 = *reinterpret_cast<const f16x8*>(&hB1[p][hb + 96]);
    f16x8 Dh0 = *reinterpret_cast<const f16x8*>(&hB2[p][hb +  0]);
    f16x8 Dh1 = *reinterpret_cast<const f16x8*>(&hB2[p][hb + 32]);
    f16x8 Dh2 = *reinterpret_cast<const f16x8*>(&hB2[p][hb + 64]);
    f16x8 Dh3 = *reinterpret_cast<const f16x8*>(&hB2[p][hb + 96]);

    f32x4n C1i = {0,0,0,0}, C1f = {0,0,0,0}, C1g = {0,0,0,0}, C1o = {0,0,0,0};
    f32x4n C2i = {0,0,0,0}, C2f = {0,0,0,0}, C2g = {0,0,0,0}, C2o = {0,0,0,0};

    // kt = 0 : 12 independent chains
    C1i = MFMA16(A1[ 0], Bh0, C1i); C1f = MFMA16(A1[ 4], Bh0, C1f);
    C1g = MFMA16(A1[ 8], Bh0, C1g); C1o = MFMA16(A1[12], Bh0, C1o);
    C2i = MFMA16(A2[ 0], Dh0, C2i); C2f = MFMA16(A2[ 4], Dh0, C2f);
    C2g = MFMA16(A2[ 8], Dh0, C2g); C2o = MFMA16(A2[12], Dh0, C2o);
    C2i = MFMA16(AI[ 0], Bh0, C2i); C2f = MFMA16(AI[ 4], Bh0, C2f);
    C2g = MFMA16(AI[ 8], Bh0, C2g); C2o = MFMA16(AI[12], Bh0, C2o);
    // kt = 1
    C1i = MFMA16(A1[ 1], Bh1, C1i); C1f = MFMA16(A1[ 5], Bh1, C1f);
    C1g = MFMA16(A1[ 9], Bh1, C1g); C1o = MFMA16(A1[13], Bh1, C1o);
    C2i = MFMA16(A2[ 1], Dh1, C2i); C2f = MFMA16(A2[ 5], Dh1, C2f);
    C2g = MFMA16(A2[ 9], Dh1, C2g); C2o = MFMA16(A2[13], Dh1, C2o);
    C2i = MFMA16(AI[ 1], Bh1, C2i); C2f = MFMA16(AI[ 5], Bh1, C2f);
    C2g = MFMA16(AI[ 9], Bh1, C2g); C2o = MFMA16(AI[13], Bh1, C2o);
    // kt = 2
    C1i = MFMA16(A1[ 2], Bh2, C1i); C1f = MFMA16(A1[ 6], Bh2, C1f);
    C1g = MFMA16(A1[10], Bh2, C1g); C1o = MFMA16(A1[14], Bh2, C1o);
    C2i = MFMA16(A2[ 2], Dh2, C2i); C2f = MFMA16(A2[ 6], Dh2, C2f);
    C2g = MFMA16(A2[10], Dh2, C2g); C2o = MFMA16(A2[14], Dh2, C2o);
    C2i = MFMA16(AI[ 2], Bh2, C2i); C2f = MFMA16(AI[ 6], Bh2, C2f);
    C2g = MFMA16(AI[10], Bh2, C2g); C2o = MFMA16(AI[14], Bh2, C2o);
    // kt = 3
    C1i = MFMA16(A1[ 3], Bh3, C1i); C1f = MFMA16(A1[ 7], Bh3, C1f);
    C1g = MFMA16(A1[11], Bh3, C1g); C1o = MFMA16(A1[15], Bh3, C1o);
    C2i = MFMA16(A2[ 3], Dh3, C2i); C2f = MFMA16(A2[ 7], Dh3, C2f);
    C2g = MFMA16(A2[11], Dh3, C2g); C2o = MFMA16(A2[15], Dh3, C2o);
    C2i = MFMA16(AI[ 3], Bh3, C2i); C2f = MFMA16(AI[ 7], Bh3, C2f);
    C2g = MFMA16(AI[11], Bh3, C2g); C2o = MFMA16(AI[15], Bh3, C2o);

    // out(t-1): 2 threads sum last step's wave partials (off critical path)
    if (tid < 2 && t > 0) {
      float sm = 0.f;
#pragma unroll
      for (int ww = 0; ww < 8; ++ww) sm += prt[p][ww][tid];
      outbuf[tid][t - 1] = sm;
    }

    // ================= act: one LSTM cell per lane, in-register ===========
    {
      float Gi[4], Gf[4], Gg[4], Go[4];
#pragma unroll
      for (int j = 0; j < 4; ++j) {
        Gi[j] = Lc ? C2i[j] : C1i[j];
        Gf[j] = Lc ? C2f[j] : C1f[j];
        Gg[j] = Lc ? C2g[j] : C1g[j];
        Go[j] = Lc ? C2o[j] : C1o[j];
      }
      float vi = (r_ == 0) ? Gi[0] : (r_ == 1) ? Gi[1] : (r_ == 2) ? Gi[2] : Gi[3];
      float vf = (r_ == 0) ? Gf[0] : (r_ == 1) ? Gf[1] : (r_ == 2) ? Gf[2] : Gf[3];
      float vg = (r_ == 0) ? Gg[0] : (r_ == 1) ? Gg[1] : (r_ == 2) ? Gg[2] : Gg[3];
      float vo = (r_ == 0) ? Go[0] : (r_ == 1) ? Go[1] : (r_ == 2) ? Go[2] : Go[3];

      int tn = (t + 1) & (T_LEN - 1);
      float xv = xbuf[b][tn];           // only matters for Lc==0 (wx==0 else)
      vi += fmaf(wx[0], xv, bc[0]);
      vf += fmaf(wx[1], xv, bc[1]);
      vg += fmaf(wx[2], xv, bc[2]);
      vo += fmaf(wx[3], xv, bc[3]);
      float si = fsig(vi), sf = fsig(vf), tg = ftanh(vg), so = fsig(vo);
      cst = fmaf(sf, cst, si * tg);
      float hv = so * ftanh(cst);
      _Float16* hp = Lc ? &hB2[pn][0] : &hB1[pn][0];
      hp[b * HB_STR + u] = (_Float16)hv;

      // out partial: layer-2 lanes contribute wo*h2; reduce all bits but b
      float po = Lc ? wo * hv : 0.f;
      po += __shfl_xor(po,  2, 64);
      po += __shfl_xor(po,  4, 64);
      po += __shfl_xor(po,  8, 64);
      po += __shfl_xor(po, 16, 64);
      po += __shfl_xor(po, 32, 64);
      if (l < 2) prt[pn][w][l] = po;    // lane0: b=0, lane1: b=1
    }
    __syncthreads();   // ---- the ONLY barrier ----
  }

  // ---- tail: out(T-1) (last step wrote parity 0) ----
  if (tid < 2) {
    float sm = 0.f;
#pragma unroll
    for (int ww = 0; ww < 8; ++ww) sm += prt[0][ww][tid];
    outbuf[tid][T_LEN - 1] = sm;
  }
  __syncthreads();

  // ---- epilogue: coalesced store ----
#pragma unroll
  for (int i = 0; i < 4; ++i) {
    int idx = tid + 512 * i;
    int bq  = idx >> 10;
    int ps  = idx & 1023;
    outp[(size_t)(b0 + bq) * T_LEN + ps] = outbuf[bq][ps] + bo;
  }
}

// ---------------------------------------------------------------------------
// Fallback (round-1, known-correct fp32 path)
// ---------------------------------------------------------------------------
__global__ void __launch_bounds__(512) transpose_w(
    const float* __restrict__ w1, const float* __restrict__ w2,
    const float* __restrict__ w3, float* __restrict__ o) {
  int m = blockIdx.y;
  const float* src = (m == 0) ? w1 : (m == 1) ? w2 : w3;
  float* dst = o + (size_t)m * G4 * HID;
  int idx = blockIdx.x * 512 + threadIdx.x;
  int j = idx >> 7;
  int k = idx & (HID - 1);
  dst[k * G4 + j] = src[idx];
}

__device__ __forceinline__ float gact(float v, int gt) {
  return (gt == 2) ? ftanh(v) : fsig(v);
}

__device__ __forceinline__ void store_out4(const float4* h2buf, float wo0, float wo1,
                                           float bo, int tid, int b0,
                                           float* __restrict__ outp, int t) {
  float4 ha = h2buf[tid];
  float4 hb = h2buf[tid + 64];
  float p0 = wo0 * ha.x + wo1 * hb.x;
  float p1 = wo0 * ha.y + wo1 * hb.y;
  float p2 = wo0 * ha.z + wo1 * hb.z;
  float p3 = wo0 * ha.w + wo1 * hb.w;
#pragma unroll
  for (int off = 1; off < 64; off <<= 1) {
    p0 += __shfl_xor(p0, off, 64);
    p1 += __shfl_xor(p1, off, 64);
    p2 += __shfl_xor(p2, off, 64);
    p3 += __shfl_xor(p3, off, 64);
  }
  if (tid < BCH) {
    float v = (tid == 0) ? p0 : (tid == 1) ? p1 : (tid == 2) ? p2 : p3;
    outp[(size_t)(b0 + tid) * T_LEN + t] = v + bo;
  }
}

__global__ void __launch_bounds__(512) lstm_fused(
    const float* __restrict__ xin, const float* __restrict__ Wih1,
    const float* __restrict__ bih1, const float* __restrict__ bhh1,
    const float* __restrict__ Whh1, const float* __restrict__ Wih2,
    const float* __restrict__ Whh2, int sk, int sj,
    const float* __restrict__ bih2, const float* __restrict__ bhh2,
    const float* __restrict__ Wout, const float* __restrict__ bout,
    float* __restrict__ outp) {
  __shared__ float4 h1buf[HID];
  __shared__ float4 h2buf[HID];
  __shared__ float4 g1[G4];
  __shared__ float4 g2[G4];
  __shared__ float xb[2][BCH];

  const int tid = threadIdx.x;
  const int b0 = blockIdx.x * BCH;
  const int gt = tid >> 7;

  float bias1 = bih1[tid] + bhh1[tid];
  float bias2 = bih2[tid] + bhh2[tid];
  float wi1 = Wih1[tid];
  float c1_0 = 0.f, c1_1 = 0.f, c1_2 = 0.f, c1_3 = 0.f;
  float c2_0 = 0.f, c2_1 = 0.f, c2_2 = 0.f, c2_3 = 0.f;
  float wo0 = 0.f, wo1 = 0.f, bo = 0.f;
  if (tid < 64) { wo0 = Wout[tid]; wo1 = Wout[tid + 64]; bo = bout[0]; }
  if (tid < HID) {
    h1buf[tid] = make_float4(0.f, 0.f, 0.f, 0.f);
    h2buf[tid] = make_float4(0.f, 0.f, 0.f, 0.f);
  }
  if (tid < BCH) xb[0][tid] = xin[(b0 + tid) * T_LEN];
  __syncthreads();

  const float* wp1  = Whh1 + tid * sj;
  const float* wp2  = Whh2 + tid * sj;
  const float* wpi2 = Wih2 + tid * sj;

  for (int t = 0; t < T_LEN; ++t) {
    float xpref = 0.f;
    if ((tid & ~3) == 128 && (t + 1) < T_LEN)
      xpref = xin[(b0 + (tid & 3)) * T_LEN + t + 1];

    if (tid < 64 && t > 0) store_out4(h2buf, wo0, wo1, bo, tid, b0, outp, t - 1);

    float xv0 = xb[t & 1][0], xv1 = xb[t & 1][1];
    float xv2 = xb[t & 1][2], xv3 = xb[t & 1][3];
    float a10 = fmaf(wi1, xv0, bias1);
    float a11 = fmaf(wi1, xv1, bias1);
    float a12 = fmaf(wi1, xv2, bias1);
    float a13 = fmaf(wi1, xv3, bias1);
    float a20 = bias2, a21 = bias2, a22 = bias2, a23 = bias2;
#pragma unroll 8
    for (int k = 0; k < HID; ++k) {
      float w1 = wp1[k * sk];
      float w2 = wp2[k * sk];
      float4 hv1 = h1buf[k];
      float4 hv2 = h2buf[k];
      a10 = fmaf(w1, hv1.x, a10);
      a11 = fmaf(w1, hv1.y, a11);
      a12 = fmaf(w1, hv1.z, a12);
      a13 = fmaf(w1, hv1.w, a13);
      a20 = fmaf(w2, hv2.x, a20);
      a21 = fmaf(w2, hv2.y, a21);
      a22 = fmaf(w2, hv2.z, a22);
      a23 = fmaf(w2, hv2.w, a23);
    }
    float4 A1v;
    A1v.x = gact(a10, gt); A1v.y = gact(a11, gt);
    A1v.z = gact(a12, gt); A1v.w = gact(a13, gt);
    g1[tid] = A1v;
    __syncthreads();

    if (tid < HID) {
      float4 iv = g1[tid], fv = g1[tid + HID];
      float4 gv = g1[tid + 2 * HID], ov = g1[tid + 3 * HID];
      c1_0 = fmaf(fv.x, c1_0, iv.x * gv.x);
      c1_1 = fmaf(fv.y, c1_1, iv.y * gv.y);
      c1_2 = fmaf(fv.z, c1_2, iv.z * gv.z);
      c1_3 = fmaf(fv.w, c1_3, iv.w * gv.w);
      float4 h;
      h.x = ov.x * ftanh(c1_0);
      h.y = ov.y * ftanh(c1_1);
      h.z = ov.z * ftanh(c1_2);
      h.w = ov.w * ftanh(c1_3);
      h1buf[tid] = h;
    }
    __syncthreads();

#pragma unroll 8
    for (int k = 0; k < HID; ++k) {
      float wv = wpi2[k * sk];
      float4 hv = h1buf[k];
      a20 = fmaf(wv, hv.x, a20);
      a21 = fmaf(wv, hv.y, a21);
      a22 = fmaf(wv, hv.z, a22);
      a23 = fmaf(wv, hv.w, a23);
    }
    float4 A2v;
    A2v.x = gact(a20, gt); A2v.y = gact(a21, gt);
    A2v.z = gact(a22, gt); A2v.w = gact(a23, gt);
    g2[tid] = A2v;
    __syncthreads();

    if (tid < HID) {
      float4 iv = g2[tid], fv = g2[tid + HID];
      float4 gv = g2[tid + 2 * HID], ov = g2[tid + 3 * HID];
      c2_0 = fmaf(fv.x, c2_0, iv.x * gv.x);
      c2_1 = fmaf(fv.y, c2_1, iv.y * gv.y);
      c2_2 = fmaf(fv.z, c2_2, iv.z * gv.z);
      c2_3 = fmaf(fv.w, c2_3, iv.w * gv.w);
      float4 h;
      h.x = ov.x * ftanh(c2_0);
      h.y = ov.y * ftanh(c2_1);
      h.z = ov.z * ftanh(c2_2);
      h.w = ov.w * ftanh(c2_3);
      h2buf[tid] = h;
    } else if ((tid & ~3) == 128 && (t + 1) < T_LEN) {
      xb[(t + 1) & 1][tid & 3] = xpref;
    }
    __syncthreads();
  }
  if (tid < 64) store_out4(h2buf, wo0, wo1, bo, tid, b0, outp, T_LEN - 1);
}

extern "C" void kernel_launch(void* const* d_in, const int* in_sizes, int n_in,
                              void* d_out, int out_size, void* d_ws, size_t ws_size,
                              hipStream_t stream) {
  const float* xin  = (const float*)d_in[0];
  const float* Wih1 = (const float*)d_in[1];
  const float* Whh1 = (const float*)d_in[2];
  const float* bih1 = (const float*)d_in[3];
  const float* bhh1 = (const float*)d_in[4];
  const float* Wih2 = (const float*)d_in[5];
  const float* Whh2 = (const float*)d_in[6];
  const float* bih2 = (const float*)d_in[7];
  const float* bhh2 = (const float*)d_in[8];
  const float* Wout = (const float*)d_in[9];
  const float* bout = (const float*)d_in[10];
  float* outp = (float*)d_out;

  const size_t needFr = (size_t)3 * 8 * 16 * 64 * sizeof(uint4);  // 384 KB
  if (ws_size >= needFr) {
    uint4* wfrag = (uint4*)d_ws;
    pack_frag2<<<96, 256, 0, stream>>>(Whh1, Whh2, Wih2, wfrag);
    lstm_v17<<<256, 512, 0, stream>>>(
        xin, Wih1, bih1, bhh1, wfrag, bih2, bhh2, Wout, bout, outp);
    return;
  }

  // fallback: round-1 fp32 kernel
  size_t need = (size_t)3 * G4 * HID * sizeof(float);
  if (ws_size >= need) {
    float* wt = (float*)d_ws;
    transpose_w<<<dim3(128, 3), 512, 0, stream>>>(Whh1, Wih2, Whh2, wt);
    lstm_fused<<<NG, 512, 0, stream>>>(
        xin, Wih1, bih1, bhh1,
        wt, wt + (size_t)G4 * HID, wt + (size_t)2 * G4 * HID, G4, 1,
        bih2, bhh2, Wout, bout, outp);
  } else {
    lstm_fused<<<NG, 512, 0, stream>>>(
        xin, Wih1, bih1, bhh1,
        Whh1, Wih2, Whh2, 1, HID,
        bih2, bhh2, Wout, bout, outp);
  }
}